// Round 11
// baseline (152.688 us; speedup 1.0000x reference)
//
#include <hip/hip_runtime.h>
#include <hip/hip_bf16.h>

#define N_NODES 100000
#define D_FEAT 64
#define CAP 64          // fallback path only
#define NBD 784         // dst buckets of 128 nodes: 784*128 = 100352 >= n
#define DB_CAP 3072     // per-dst-bucket record cap (mean 2176, +19 sigma) == LDS CSR cap
#define NBS 392         // src buckets of 256 nodes: 392*256 = 100352 >= n+1
#define SB_CAP 5500     // per-src-bucket record cap (mean 4336, +17 sigma)
#define PT 512          // partition threads per block
#define EPT 7           // edges register-cached per thread; chunk = EPT*PT = 3584
                        // NOTE round 9: chunk/NBD is the flush run length (4.6
                        // here); EPT=4 + NBD=1568 gave runs of 1.3 -> scatter
                        // returned, partition 30->54 us.  Keep this pairing.

typedef unsigned int uint;
typedef unsigned short ushort;

// fp32 -> bf16 round-to-nearest-even
__device__ __forceinline__ uint f2bf(float f) {
    uint u = __float_as_uint(f);
    return (u + 0x7fffu + ((u >> 16) & 1u)) >> 16;
}

// ========== pass 1: coarse partition with LDS-staged coalesced flush =======
// (round-8 proven form: rank-capture + bucket-sorted LDS staging + linear
// flush.  All per-edge atomics in LDS -- rounds 2+4 lessons.)
__global__ __launch_bounds__(PT) void
partition_kernel(const int* __restrict__ src, const int* __restrict__ dst,
                 int* __restrict__ dstCur, int* __restrict__ srcCur,
                 uint* __restrict__ dstrec, ushort* __restrict__ srcrec,
                 int nE) {
    __shared__ int hd[NBD], bd[NBD], hs[NBS], bs[NBS];   // 9.4 KB
    __shared__ uint2 pairD[EPT * PT];                    // 28 KB, reused for src
    const int t = threadIdx.x;
    const int wv = t >> 6, lane = t & 63;
    for (int i = t; i < NBD; i += PT) hd[i] = 0;
    for (int i = t; i < NBS; i += PT) hs[i] = 0;
    __syncthreads();
    const int beg = blockIdx.x * (EPT * PT);
    const int tot = min(nE - beg, EPT * PT);             // valid edges this block
    int se[EPT], de[EPT], rd[EPT], rs[EPT];
#pragma unroll
    for (int k = 0; k < EPT; ++k) {
        int e = beg + t + k * PT;
        int s = 0, d = 0, r1 = 0, r2 = 0;
        if (e < nE) {
            s = src[e]; d = dst[e];                // coalesced
            r1 = atomicAdd(&hd[d >> 7], 1);        // rank within (block, dst-bucket)
            r2 = atomicAdd(&hs[s >> 8], 1);        // rank within (block, src-bucket)
        }
        se[k] = s; de[k] = d; rd[k] = r1; rs[k] = r2;
    }
    __syncthreads();
    for (int i = t; i < NBD; i += PT) bd[i] = atomicAdd(&dstCur[i], hd[i]);
    for (int i = t; i < NBS; i += PT) bs[i] = atomicAdd(&srcCur[i], hs[i]);
    __syncthreads();
    // in-place exclusive scans: hd/hs become LDS-CSR bases (wave 0: dst, wave 1: src)
    if (wv == 0) {
        int carry = 0;
        for (int c0 = 0; c0 < NBD; c0 += 64) {
            int idx = c0 + lane;
            int v = (idx < NBD) ? hd[idx] : 0;
            int sc = v;
            for (int d = 1; d < 64; d <<= 1) {
                int u = __shfl_up(sc, d, 64);
                if (lane >= d) sc += u;
            }
            if (idx < NBD) hd[idx] = sc - v + carry;     // exclusive
            carry += __shfl(sc, 63, 64);
        }
    } else if (wv == 1) {
        int carry = 0;
        for (int c0 = 0; c0 < NBS; c0 += 64) {
            int idx = c0 + lane;
            int v = (idx < NBS) ? hs[idx] : 0;
            int sc = v;
            for (int d = 1; d < 64; d <<= 1) {
                int u = __shfl_up(sc, d, 64);
                if (lane >= d) sc += u;
            }
            if (idx < NBS) hs[idx] = sc - v + carry;
            carry += __shfl(sc, 63, 64);
        }
    }
    __syncthreads();
    // stage dst records bucket-sorted: LDS pos = scanD[b]+rank; addr = global slot
#pragma unroll
    for (int k = 0; k < EPT; ++k) {
        int e = beg + t + k * PT;
        if (e < nE) {
            int d = de[k], s = se[k];
            int b = d >> 7;
            int p = bd[b] + rd[k];
            uint addr = (p < DB_CAP) ? (uint)(b * DB_CAP + p) : 0xFFFFFFFFu;
            uint2 pr; pr.x = addr; pr.y = ((uint)(d & 127) << 17) | (uint)s;  // s < 2^17
            pairD[hd[b] + rd[k]] = pr;
        }
    }
    __syncthreads();
    for (int j = t; j < tot; j += PT) {                  // coalesced flush
        uint2 pr = pairD[j];
        if (pr.x != 0xFFFFFFFFu) dstrec[pr.x] = pr.y;
    }
    __syncthreads();                                     // before buffer reuse
    // stage src records (packed addr<<8 | payload; addr < 2.16M < 2^24)
    uint* bufS = (uint*)pairD;
#pragma unroll
    for (int k = 0; k < EPT; ++k) {
        int e = beg + t + k * PT;
        if (e < nE) {
            int s = se[k];
            int b2 = s >> 8;
            int p2 = bs[b2] + rs[k];
            uint addr = (p2 < SB_CAP) ? (uint)(b2 * SB_CAP + p2) : 0xFFFFFFu;
            bufS[hs[b2] + rs[k]] = (addr << 8) | (uint)(s & 255);
        }
    }
    __syncthreads();
    for (int j = t; j < tot; j += PT) {
        uint v = bufS[j];
        uint a = v >> 8;
        if (a < (uint)(NBS * SB_CAP)) srcrec[a] = (ushort)(v & 255);
    }
}

// ========== pass 2: src-degree histogram + prescale (half-bucket blocks) ===
// (round-10 proven: 2 blocks per 256-node bucket, grid 784 = 3.06/CU)
__global__ __launch_bounds__(512) void
prescale_kernel(const ushort* __restrict__ srcrec, const int* __restrict__ srcCur,
                const float* __restrict__ feat, uint2* __restrict__ xb, int n) {
    __shared__ int lc[128];
    const int t = threadIdx.x;
    const int b = blockIdx.x >> 1;                // bucket
    const int hb = (blockIdx.x & 1) << 7;         // half selector: 0 or 128
    const int base = (b << 8) + hb;
    if (t < 128) lc[t] = 0;
    __syncthreads();
    int cnt = min(srcCur[b], SB_CAP);
    const uint* rec2 = (const uint*)(srcrec + (size_t)b * SB_CAP);  // SB_CAP even -> aligned
    const int pairs = cnt >> 1;
    for (int i = t; i < pairs; i += 512) {
        uint rr = rec2[i];
        int a = (int)(rr & 0xFFu);
        int c = (int)((rr >> 16) & 0xFFu);
        if ((a & 128) == hb) atomicAdd(&lc[a & 127], 1);
        if ((c & 128) == hb) atomicAdd(&lc[c & 127], 1);
    }
    if ((cnt & 1) && t == 0) {
        int a = srcrec[(size_t)b * SB_CAP + cnt - 1];
        if ((a & 128) == hb) atomicAdd(&lc[a & 127], 1);
    }
    __syncthreads();
    const int rows = min(128, n + 1 - base);      // includes pad row n; <=0 past it
    const int d4 = t & 15;
    for (int r = t >> 4; r < rows; r += 32) {     // coalesced 1KB/wave
        const int row = base + r;
        uint2 o;
        if (row == n) {
            o.x = 0u; o.y = 0u;
        } else {
            float w = rsqrtf((float)max(lc[r], 1));
            float4 v = ((const float4*)feat)[(size_t)row * 16 + d4];
            o.x = f2bf(w * v.x) | (f2bf(w * v.y) << 16);
            o.y = f2bf(w * v.z) | (f2bf(w * v.w) << 16);
        }
        xb[(size_t)row * 16 + d4] = o;
    }
}

// ========== pass 3: fused bin + gather, one block per 128-node dst bucket ==
// Phase A: LDS histogram -> wave-0 shfl scan -> LDS-CSR placement (proven).
// Phase B (NEW): one ROW per 16-lane sub-group -- each wave processes 4 rows
//   simultaneously, each sub streams its own row's edge list with an 8-deep
//   load pipeline (up to 32 lines in flight/wave).  The cross-sub shfl_xor
//   reduce (128 cross-lane ops/wave) and the 16 per-row pipeline-drain
//   bubbles are gone; k-loop 16 -> 4.  Trip-count divergence across subs
//   (max-of-4 Poisson) is the cheaper trade.
__global__ __launch_bounds__(512) void
binGather_kernel(const uint* __restrict__ dstrec, const int* __restrict__ dstCur,
                 const uint2* __restrict__ xb, float* __restrict__ out, int n) {
    __shared__ int cnt[128], off[128];
    __shared__ int eLDS[DB_CAP];                       // 12 KB
    const int t = threadIdx.x;
    const int b = blockIdx.x;
    const int base = b << 7;
    if (t < 128) cnt[t] = 0;
    __syncthreads();
    const int nr = min(dstCur[b], DB_CAP);
    const uint* rec = dstrec + (size_t)b * DB_CAP;
    for (int i = t; i < nr; i += 512) atomicAdd(&cnt[rec[i] >> 17], 1);
    __syncthreads();
    if (t < 64) {                                      // wave-0 exclusive scan of cnt[0..127]
        int v0 = cnt[t], v1 = cnt[64 + t];
        int s0 = v0, s1 = v1;
        for (int d = 1; d < 64; d <<= 1) {
            int u0 = __shfl_up(s0, d, 64);
            int u1 = __shfl_up(s1, d, 64);
            if (t >= d) { s0 += u0; s1 += u1; }
        }
        int tot0 = __shfl(s0, 63, 64);
        off[t]      = s0 - v0;
        off[64 + t] = tot0 + s1 - v1;
    }
    __syncthreads();
    for (int i = t; i < nr; i += 512) {                // CSR placement
        uint r = rec[i];
        int p = atomicAdd(&off[r >> 17], 1);           // off becomes end-pointer
        eLDS[p] = (int)(r & 0x1FFFF);
    }
    __syncthreads();

#define ACC8(v)                                        \
    acc.x += __uint_as_float((v).x << 16);             \
    acc.y += __uint_as_float((v).x & 0xffff0000u);     \
    acc.z += __uint_as_float((v).y << 16);             \
    acc.w += __uint_as_float((v).y & 0xffff0000u);

    // gather: 8 waves x 4 iterations x 4 rows; 16 lanes own one full row
    const int wv = t >> 6, lane = t & 63, sub = lane >> 4, d4 = lane & 15;
    for (int k = 0; k < 4; ++k) {
        const int r = wv * 16 + k * 4 + sub;           // per-sub row
        const int row = base + r;
        const int c = cnt[r];                          // 0 for rows past n (no records)
        const int start = off[r] - c;                  // off[r] = start + c after placement
        float4 acc = {0.f, 0.f, 0.f, 0.f};
        int i = 0;
        for (; i + 7 < c; i += 8) {                    // 8 edges in flight per sub
            int s0 = eLDS[start + i];                  // 16-lane same-addr broadcast
            int s1 = eLDS[start + i + 1];
            int s2 = eLDS[start + i + 2];
            int s3 = eLDS[start + i + 3];
            int s4 = eLDS[start + i + 4];
            int s5 = eLDS[start + i + 5];
            int s6 = eLDS[start + i + 6];
            int s7 = eLDS[start + i + 7];
            uint2 v0 = xb[(size_t)s0 * 16 + d4];
            uint2 v1 = xb[(size_t)s1 * 16 + d4];
            uint2 v2 = xb[(size_t)s2 * 16 + d4];
            uint2 v3 = xb[(size_t)s3 * 16 + d4];
            uint2 v4 = xb[(size_t)s4 * 16 + d4];
            uint2 v5 = xb[(size_t)s5 * 16 + d4];
            uint2 v6 = xb[(size_t)s6 * 16 + d4];
            uint2 v7 = xb[(size_t)s7 * 16 + d4];
            ACC8(v0); ACC8(v1); ACC8(v2); ACC8(v3);
            ACC8(v4); ACC8(v5); ACC8(v6); ACC8(v7);
        }
        for (; i + 1 < c; i += 2) {                    // 2-deep tail
            int s0 = eLDS[start + i];
            int s1 = eLDS[start + i + 1];
            uint2 v0 = xb[(size_t)s0 * 16 + d4];
            uint2 v1 = xb[(size_t)s1 * 16 + d4];
            ACC8(v0); ACC8(v1);
        }
        if (i < c) {
            int s0 = eLDS[start + i];
            uint2 v0 = xb[(size_t)s0 * 16 + d4];
            ACC8(v0);
        }
        if (row < n) {
            float si = rsqrtf((float)max(c, 1));       // rs_in
            float4 rr = { acc.x * si, acc.y * si, acc.z * si, acc.w * si };
            ((float4*)out)[(size_t)row * 16 + d4] = rr;
        }
    }
#undef ACC8
}

// ========== fallback: R8's proven single-pass fp32 path ====================
__global__ void bucket_kernel(const int* __restrict__ src, const int* __restrict__ dst,
                              int* __restrict__ cursor, int* __restrict__ deg_out,
                              int* __restrict__ edge_src, int nE) {
    int e = blockIdx.x * blockDim.x + threadIdx.x;
    if (e < nE) {
        int s = src[e];
        int d = dst[e];
        atomicAdd(&deg_out[s], 1);
        int pos = atomicAdd(&cursor[d], 1);
        if (pos < CAP) edge_src[(size_t)d * CAP + pos] = s;
    }
}

__global__ void gather_cap_kernel(const float* __restrict__ feat,
                                  const int* __restrict__ edge_src,
                                  const int* __restrict__ cursor,
                                  const int* __restrict__ deg_out,
                                  float* __restrict__ out, int n) {
    int wave = (blockIdx.x * blockDim.x + threadIdx.x) >> 6;
    if (wave >= n) return;
    int lane = threadIdx.x & 63;
    int cnt = min(cursor[wave], CAP);

    int   s_l = (lane < cnt) ? edge_src[(size_t)wave * CAP + lane] : 0;
    float w_l = (lane < cnt) ? rsqrtf((float)max(deg_out[s_l], 1)) : 0.0f;

    int sub = lane >> 4;
    int d4  = lane & 15;
    float4 a0 = {0.f,0.f,0.f,0.f}, a1 = {0.f,0.f,0.f,0.f};

    for (int i = 0; i < cnt; i += 8) {
        int   s0 = __shfl(s_l, i + sub, 64);
        float w0 = __shfl(w_l, i + sub, 64);
        int   s1 = __shfl(s_l, i + sub + 4, 64);
        float w1 = __shfl(w_l, i + sub + 4, 64);
        float4 v0 = ((const float4*)feat)[(size_t)s0 * 16 + d4];
        float4 v1 = ((const float4*)feat)[(size_t)s1 * 16 + d4];
        a0.x += w0 * v0.x; a0.y += w0 * v0.y; a0.z += w0 * v0.z; a0.w += w0 * v0.w;
        a1.x += w1 * v1.x; a1.y += w1 * v1.y; a1.z += w1 * v1.z; a1.w += w1 * v1.w;
    }
    float4 acc = { a0.x + a1.x, a0.y + a1.y, a0.z + a1.z, a0.w + a1.w };
    for (int off = 16; off < 64; off <<= 1) {
        acc.x += __shfl_xor(acc.x, off, 64);
        acc.y += __shfl_xor(acc.y, off, 64);
        acc.z += __shfl_xor(acc.z, off, 64);
        acc.w += __shfl_xor(acc.w, off, 64);
    }
    if (sub == 0) {
        float si = rsqrtf((float)max(cnt, 1));
        float4 r = { acc.x * si, acc.y * si, acc.z * si, acc.w * si };
        ((float4*)out)[(size_t)wave * 16 + d4] = r;
    }
}

// ===========================================================================

extern "C" void kernel_launch(void* const* d_in, const int* in_sizes, int n_in,
                              void* d_out, int out_size, void* d_ws, size_t ws_size,
                              hipStream_t stream) {
    const float* feat = (const float*)d_in[0];
    const int*   src  = (const int*)d_in[1];
    const int*   dst  = (const int*)d_in[2];
    float* out = (float*)d_out;
    const int nE = in_sizes[1];
    const int n  = N_NODES;

    // Fast-path layout (512-B aligned sections; xb rows must not straddle
    // cache lines -- round 1 proved a misaligned xb costs ~14 us):
    //   dstCur[NBD] srcCur[NBS] | dstrec | srcrec | xb
    const size_t ctr_bytes = (NBD + NBS) * sizeof(int);               // 4704
    const size_t dr_off    = (ctr_bytes + 511) & ~(size_t)511;
    const size_t dr_sz     = (size_t)NBD * DB_CAP * sizeof(uint);     // 9,633,792
    const size_t sr_off    = dr_off + dr_sz;                          // 512-mult
    const size_t sr_sz     = (size_t)NBS * SB_CAP * sizeof(ushort);   // 4,312,000
    const size_t xb_off    = (sr_off + sr_sz + 511) & ~(size_t)511;
    const size_t xb_bytes  = (size_t)(n + 1) * 16 * sizeof(uint2);    // 12,800,128
    const size_t need_new  = xb_off + xb_bytes;                       // ~26.8 MB
    const size_t need_fp   = (size_t)n * (2 + CAP) * sizeof(int);     // ~26.4 MB

    if (ws_size >= need_new) {
        char*   W        = (char*)d_ws;
        int*    dstCur   = (int*)W;
        int*    srcCur   = dstCur + NBD;
        uint*   dstrec   = (uint*)(W + dr_off);
        ushort* srcrec   = (ushort*)(W + sr_off);
        uint2*  xb       = (uint2*)(W + xb_off);

        hipMemsetAsync(dstCur, 0, ctr_bytes, stream);
        {
            const int chunk = EPT * PT;                       // 3584
            const int grid = (nE + chunk - 1) / chunk;        // 475 for 1.7M edges
            partition_kernel<<<grid, PT, 0, stream>>>(src, dst, dstCur, srcCur,
                                                      dstrec, srcrec, nE);
        }
        prescale_kernel<<<2 * NBS, 512, 0, stream>>>(srcrec, srcCur, feat, xb, n);
        binGather_kernel<<<NBD, 512, 0, stream>>>(dstrec, dstCur, xb, out, n);
    } else if (ws_size >= need_fp) {
        // R8's proven fp32 path: cursor[n] | deg_out[n] | edge_src[n*CAP]
        int* cursor   = (int*)d_ws;
        int* deg_out  = cursor + n;
        int* edge_src = deg_out + n;

        hipMemsetAsync(cursor, 0, 2 * (size_t)n * sizeof(int), stream);
        {
            int block = 256, grid = (nE + block - 1) / block;
            bucket_kernel<<<grid, block, 0, stream>>>(src, dst, cursor, deg_out, edge_src, nE);
        }
        {
            int block = 256, grid = (n + 3) / 4;
            gather_cap_kernel<<<grid, block, 0, stream>>>(feat, edge_src, cursor, deg_out, out, n);
        }
    }
}

// Round 12
// 151.360 us; speedup vs baseline: 1.0088x; 1.0088x over previous
//
#include <hip/hip_runtime.h>
#include <hip/hip_bf16.h>

#define N_NODES 100000
#define D_FEAT 64
#define CAP 64          // fallback path only
#define NBD 784         // dst buckets of 128 nodes: 784*128 = 100352 >= n
#define DB_CAP 3072     // per-dst-bucket record cap (mean 2176, +19 sigma)
#define HB_CAP 2048     // per HALF-bucket (64 nodes) LDS CSR cap (mean 1088, +29 sigma)
#define NBS 392         // src buckets of 256 nodes: 392*256 = 100352 >= n+1
#define SB_CAP 5500     // per-src-bucket record cap (mean 4336, +17 sigma)
#define PT 512          // partition threads per block
#define EPT 7           // edges register-cached per thread; chunk = EPT*PT = 3584
                        // NOTE round 9: chunk/NBD is the flush run length (4.6
                        // here); EPT=4 + NBD=1568 gave runs of 1.3 -> scatter
                        // returned, partition 30->54 us.  Keep this pairing.

typedef unsigned int uint;
typedef unsigned short ushort;

// fp32 -> bf16 round-to-nearest-even
__device__ __forceinline__ uint f2bf(float f) {
    uint u = __float_as_uint(f);
    return (u + 0x7fffu + ((u >> 16) & 1u)) >> 16;
}

// ========== pass 1: coarse partition with LDS-staged coalesced flush =======
// (round-8 proven form: rank-capture + bucket-sorted LDS staging + linear
// flush.  All per-edge atomics in LDS -- rounds 2+4 lessons.)
__global__ __launch_bounds__(PT) void
partition_kernel(const int* __restrict__ src, const int* __restrict__ dst,
                 int* __restrict__ dstCur, int* __restrict__ srcCur,
                 uint* __restrict__ dstrec, ushort* __restrict__ srcrec,
                 int nE) {
    __shared__ int hd[NBD], bd[NBD], hs[NBS], bs[NBS];   // 9.4 KB
    __shared__ uint2 pairD[EPT * PT];                    // 28 KB, reused for src
    const int t = threadIdx.x;
    const int wv = t >> 6, lane = t & 63;
    for (int i = t; i < NBD; i += PT) hd[i] = 0;
    for (int i = t; i < NBS; i += PT) hs[i] = 0;
    __syncthreads();
    const int beg = blockIdx.x * (EPT * PT);
    const int tot = min(nE - beg, EPT * PT);             // valid edges this block
    int se[EPT], de[EPT], rd[EPT], rs[EPT];
#pragma unroll
    for (int k = 0; k < EPT; ++k) {
        int e = beg + t + k * PT;
        int s = 0, d = 0, r1 = 0, r2 = 0;
        if (e < nE) {
            s = src[e]; d = dst[e];                // coalesced
            r1 = atomicAdd(&hd[d >> 7], 1);        // rank within (block, dst-bucket)
            r2 = atomicAdd(&hs[s >> 8], 1);        // rank within (block, src-bucket)
        }
        se[k] = s; de[k] = d; rd[k] = r1; rs[k] = r2;
    }
    __syncthreads();
    for (int i = t; i < NBD; i += PT) bd[i] = atomicAdd(&dstCur[i], hd[i]);
    for (int i = t; i < NBS; i += PT) bs[i] = atomicAdd(&srcCur[i], hs[i]);
    __syncthreads();
    // in-place exclusive scans: hd/hs become LDS-CSR bases (wave 0: dst, wave 1: src)
    if (wv == 0) {
        int carry = 0;
        for (int c0 = 0; c0 < NBD; c0 += 64) {
            int idx = c0 + lane;
            int v = (idx < NBD) ? hd[idx] : 0;
            int sc = v;
            for (int d = 1; d < 64; d <<= 1) {
                int u = __shfl_up(sc, d, 64);
                if (lane >= d) sc += u;
            }
            if (idx < NBD) hd[idx] = sc - v + carry;     // exclusive
            carry += __shfl(sc, 63, 64);
        }
    } else if (wv == 1) {
        int carry = 0;
        for (int c0 = 0; c0 < NBS; c0 += 64) {
            int idx = c0 + lane;
            int v = (idx < NBS) ? hs[idx] : 0;
            int sc = v;
            for (int d = 1; d < 64; d <<= 1) {
                int u = __shfl_up(sc, d, 64);
                if (lane >= d) sc += u;
            }
            if (idx < NBS) hs[idx] = sc - v + carry;
            carry += __shfl(sc, 63, 64);
        }
    }
    __syncthreads();
    // stage dst records bucket-sorted: LDS pos = scanD[b]+rank; addr = global slot
#pragma unroll
    for (int k = 0; k < EPT; ++k) {
        int e = beg + t + k * PT;
        if (e < nE) {
            int d = de[k], s = se[k];
            int b = d >> 7;
            int p = bd[b] + rd[k];
            uint addr = (p < DB_CAP) ? (uint)(b * DB_CAP + p) : 0xFFFFFFFFu;
            uint2 pr; pr.x = addr; pr.y = ((uint)(d & 127) << 17) | (uint)s;  // s < 2^17
            pairD[hd[b] + rd[k]] = pr;
        }
    }
    __syncthreads();
    for (int j = t; j < tot; j += PT) {                  // coalesced flush
        uint2 pr = pairD[j];
        if (pr.x != 0xFFFFFFFFu) dstrec[pr.x] = pr.y;
    }
    __syncthreads();                                     // before buffer reuse
    // stage src records (packed addr<<8 | payload; addr < 2.16M < 2^24)
    uint* bufS = (uint*)pairD;
#pragma unroll
    for (int k = 0; k < EPT; ++k) {
        int e = beg + t + k * PT;
        if (e < nE) {
            int s = se[k];
            int b2 = s >> 8;
            int p2 = bs[b2] + rs[k];
            uint addr = (p2 < SB_CAP) ? (uint)(b2 * SB_CAP + p2) : 0xFFFFFFu;
            bufS[hs[b2] + rs[k]] = (addr << 8) | (uint)(s & 255);
        }
    }
    __syncthreads();
    for (int j = t; j < tot; j += PT) {
        uint v = bufS[j];
        uint a = v >> 8;
        if (a < (uint)(NBS * SB_CAP)) srcrec[a] = (ushort)(v & 255);
    }
}

// ========== pass 2: src-degree histogram + prescale (half-bucket blocks) ===
// (round-10 proven: 2 blocks per 256-node bucket, grid 784 = 3.06/CU)
__global__ __launch_bounds__(512) void
prescale_kernel(const ushort* __restrict__ srcrec, const int* __restrict__ srcCur,
                const float* __restrict__ feat, uint2* __restrict__ xb, int n) {
    __shared__ int lc[128];
    const int t = threadIdx.x;
    const int b = blockIdx.x >> 1;                // bucket
    const int hb = (blockIdx.x & 1) << 7;         // half selector: 0 or 128
    const int base = (b << 8) + hb;
    if (t < 128) lc[t] = 0;
    __syncthreads();
    int cnt = min(srcCur[b], SB_CAP);
    const uint* rec2 = (const uint*)(srcrec + (size_t)b * SB_CAP);  // SB_CAP even -> aligned
    const int pairs = cnt >> 1;
    for (int i = t; i < pairs; i += 512) {
        uint rr = rec2[i];
        int a = (int)(rr & 0xFFu);
        int c = (int)((rr >> 16) & 0xFFu);
        if ((a & 128) == hb) atomicAdd(&lc[a & 127], 1);
        if ((c & 128) == hb) atomicAdd(&lc[c & 127], 1);
    }
    if ((cnt & 1) && t == 0) {
        int a = srcrec[(size_t)b * SB_CAP + cnt - 1];
        if ((a & 128) == hb) atomicAdd(&lc[a & 127], 1);
    }
    __syncthreads();
    const int rows = min(128, n + 1 - base);      // includes pad row n; <=0 past it
    const int d4 = t & 15;
    for (int r = t >> 4; r < rows; r += 32) {     // coalesced 1KB/wave
        const int row = base + r;
        uint2 o;
        if (row == n) {
            o.x = 0u; o.y = 0u;
        } else {
            float w = rsqrtf((float)max(lc[r], 1));
            float4 v = ((const float4*)feat)[(size_t)row * 16 + d4];
            o.x = f2bf(w * v.x) | (f2bf(w * v.y) << 16);
            o.y = f2bf(w * v.z) | (f2bf(w * v.w) << 16);
        }
        xb[(size_t)row * 16 + d4] = o;
    }
}

// ========== pass 3: fused bin + gather, TWO blocks per 128-node dst bucket =
// Round-11 lesson: per-sub-row streaming (trip divergence) is NOT better
// than the round-8 16-lane/cross-sub form -- phase B reverted to round-8.
// NEW: half-bucket split (the same trick that fixed prescale in round 10).
// Each half-block re-reads the bucket's records (L2-resident, ~+9 MB total)
// but histograms/places/gathers only its 64 rows: grid 784 -> 1568 (6.1/CU
// vs measured 40% occupancy), half the phase-A atomics and phase-B serial
// depth per block, 12.5 KB LDS.
__global__ __launch_bounds__(512) void
binGather_kernel(const uint* __restrict__ dstrec, const int* __restrict__ dstCur,
                 const uint2* __restrict__ xb, float* __restrict__ out, int n) {
    __shared__ int cnt[64], off[64];
    __shared__ int eLDS[HB_CAP];                       // 8 KB
    const int t = threadIdx.x;
    const int b  = blockIdx.x >> 1;                    // bucket
    const int hbit = (blockIdx.x & 1) << 6;            // half selector: 0 or 64
    const int base = (b << 7) + hbit;
    if (t < 64) cnt[t] = 0;
    __syncthreads();
    const int nr = min(dstCur[b], DB_CAP);
    const uint* rec = dstrec + (size_t)b * DB_CAP;
    for (int i = t; i < nr; i += 512) {
        int dl = (int)(rec[i] >> 17);
        if ((dl & 64) == hbit) atomicAdd(&cnt[dl & 63], 1);
    }
    __syncthreads();
    if (t < 64) {                                      // single-wave exclusive scan
        int v0 = cnt[t];
        int s0 = v0;
        for (int d = 1; d < 64; d <<= 1) {
            int u0 = __shfl_up(s0, d, 64);
            if (t >= d) s0 += u0;
        }
        off[t] = s0 - v0;
    }
    __syncthreads();
    for (int i = t; i < nr; i += 512) {                // CSR placement (our half only)
        uint r = rec[i];
        int dl = (int)(r >> 17);
        if ((dl & 64) == hbit) {
            int p = atomicAdd(&off[dl & 63], 1);       // off becomes end-pointer
            if (p < HB_CAP) eLDS[p] = (int)(r & 0x1FFFF);
        }
    }
    __syncthreads();

#define ACC8(v)                                        \
    acc.x += __uint_as_float((v).x << 16);             \
    acc.y += __uint_as_float((v).x & 0xffff0000u);     \
    acc.z += __uint_as_float((v).y << 16);             \
    acc.w += __uint_as_float((v).y & 0xffff0000u);

    // gather: 8 waves x 8 interleaved rows; 16 lanes per row (uint2), 4-deep
    const int wv = t >> 6, lane = t & 63, sub = lane >> 4, d4 = lane & 15;
    for (int k = 0; k < 8; ++k) {
        const int r = wv + (k << 3);                   // wave-uniform local row 0..63
        const int row = base + r;
        if (row >= n) continue;
        const int c = cnt[r];
        const int start = off[r] - c;                  // off[r] = start + c after placement
        float4 acc = {0.f, 0.f, 0.f, 0.f};
        int i = sub;
        for (; i + 12 < c; i += 16) {                  // 4 rows in flight per sub-group
            int s0 = eLDS[start + i];                  // 16-lane LDS broadcast
            int s1 = eLDS[start + i + 4];
            int s2 = eLDS[start + i + 8];
            int s3 = eLDS[start + i + 12];
            uint2 v0 = xb[(size_t)s0 * 16 + d4];
            uint2 v1 = xb[(size_t)s1 * 16 + d4];
            uint2 v2 = xb[(size_t)s2 * 16 + d4];
            uint2 v3 = xb[(size_t)s3 * 16 + d4];
            ACC8(v0); ACC8(v1); ACC8(v2); ACC8(v3);
        }
        for (; i < c; i += 4) {                        // tail: 1 row in flight
            int s0 = eLDS[start + i];
            uint2 v0 = xb[(size_t)s0 * 16 + d4];
            ACC8(v0);
        }
        for (int o = 16; o < 64; o <<= 1) {            // reduce across 4 sub-groups
            acc.x += __shfl_xor(acc.x, o, 64);
            acc.y += __shfl_xor(acc.y, o, 64);
            acc.z += __shfl_xor(acc.z, o, 64);
            acc.w += __shfl_xor(acc.w, o, 64);
        }
        if (sub == 0) {
            float si = rsqrtf((float)max(c, 1));       // rs_in
            float4 rr = { acc.x * si, acc.y * si, acc.z * si, acc.w * si };
            ((float4*)out)[(size_t)row * 16 + d4] = rr;
        }
    }
#undef ACC8
}

// ========== fallback: R8's proven single-pass fp32 path ====================
__global__ void bucket_kernel(const int* __restrict__ src, const int* __restrict__ dst,
                              int* __restrict__ cursor, int* __restrict__ deg_out,
                              int* __restrict__ edge_src, int nE) {
    int e = blockIdx.x * blockDim.x + threadIdx.x;
    if (e < nE) {
        int s = src[e];
        int d = dst[e];
        atomicAdd(&deg_out[s], 1);
        int pos = atomicAdd(&cursor[d], 1);
        if (pos < CAP) edge_src[(size_t)d * CAP + pos] = s;
    }
}

__global__ void gather_cap_kernel(const float* __restrict__ feat,
                                  const int* __restrict__ edge_src,
                                  const int* __restrict__ cursor,
                                  const int* __restrict__ deg_out,
                                  float* __restrict__ out, int n) {
    int wave = (blockIdx.x * blockDim.x + threadIdx.x) >> 6;
    if (wave >= n) return;
    int lane = threadIdx.x & 63;
    int cnt = min(cursor[wave], CAP);

    int   s_l = (lane < cnt) ? edge_src[(size_t)wave * CAP + lane] : 0;
    float w_l = (lane < cnt) ? rsqrtf((float)max(deg_out[s_l], 1)) : 0.0f;

    int sub = lane >> 4;
    int d4  = lane & 15;
    float4 a0 = {0.f,0.f,0.f,0.f}, a1 = {0.f,0.f,0.f,0.f};

    for (int i = 0; i < cnt; i += 8) {
        int   s0 = __shfl(s_l, i + sub, 64);
        float w0 = __shfl(w_l, i + sub, 64);
        int   s1 = __shfl(s_l, i + sub + 4, 64);
        float w1 = __shfl(w_l, i + sub + 4, 64);
        float4 v0 = ((const float4*)feat)[(size_t)s0 * 16 + d4];
        float4 v1 = ((const float4*)feat)[(size_t)s1 * 16 + d4];
        a0.x += w0 * v0.x; a0.y += w0 * v0.y; a0.z += w0 * v0.z; a0.w += w0 * v0.w;
        a1.x += w1 * v1.x; a1.y += w1 * v1.y; a1.z += w1 * v1.z; a1.w += w1 * v1.w;
    }
    float4 acc = { a0.x + a1.x, a0.y + a1.y, a0.z + a1.z, a0.w + a1.w };
    for (int off = 16; off < 64; off <<= 1) {
        acc.x += __shfl_xor(acc.x, off, 64);
        acc.y += __shfl_xor(acc.y, off, 64);
        acc.z += __shfl_xor(acc.z, off, 64);
        acc.w += __shfl_xor(acc.w, off, 64);
    }
    if (sub == 0) {
        float si = rsqrtf((float)max(cnt, 1));
        float4 r = { acc.x * si, acc.y * si, acc.z * si, acc.w * si };
        ((float4*)out)[(size_t)wave * 16 + d4] = r;
    }
}

// ===========================================================================

extern "C" void kernel_launch(void* const* d_in, const int* in_sizes, int n_in,
                              void* d_out, int out_size, void* d_ws, size_t ws_size,
                              hipStream_t stream) {
    const float* feat = (const float*)d_in[0];
    const int*   src  = (const int*)d_in[1];
    const int*   dst  = (const int*)d_in[2];
    float* out = (float*)d_out;
    const int nE = in_sizes[1];
    const int n  = N_NODES;

    // Fast-path layout (512-B aligned sections; xb rows must not straddle
    // cache lines -- round 1 proved a misaligned xb costs ~14 us):
    //   dstCur[NBD] srcCur[NBS] | dstrec | srcrec | xb
    const size_t ctr_bytes = (NBD + NBS) * sizeof(int);               // 4704
    const size_t dr_off    = (ctr_bytes + 511) & ~(size_t)511;
    const size_t dr_sz     = (size_t)NBD * DB_CAP * sizeof(uint);     // 9,633,792
    const size_t sr_off    = dr_off + dr_sz;                          // 512-mult
    const size_t sr_sz     = (size_t)NBS * SB_CAP * sizeof(ushort);   // 4,312,000
    const size_t xb_off    = (sr_off + sr_sz + 511) & ~(size_t)511;
    const size_t xb_bytes  = (size_t)(n + 1) * 16 * sizeof(uint2);    // 12,800,128
    const size_t need_new  = xb_off + xb_bytes;                       // ~26.8 MB
    const size_t need_fp   = (size_t)n * (2 + CAP) * sizeof(int);     // ~26.4 MB

    if (ws_size >= need_new) {
        char*   W        = (char*)d_ws;
        int*    dstCur   = (int*)W;
        int*    srcCur   = dstCur + NBD;
        uint*   dstrec   = (uint*)(W + dr_off);
        ushort* srcrec   = (ushort*)(W + sr_off);
        uint2*  xb       = (uint2*)(W + xb_off);

        hipMemsetAsync(dstCur, 0, ctr_bytes, stream);
        {
            const int chunk = EPT * PT;                       // 3584
            const int grid = (nE + chunk - 1) / chunk;        // 475 for 1.7M edges
            partition_kernel<<<grid, PT, 0, stream>>>(src, dst, dstCur, srcCur,
                                                      dstrec, srcrec, nE);
        }
        prescale_kernel<<<2 * NBS, 512, 0, stream>>>(srcrec, srcCur, feat, xb, n);
        binGather_kernel<<<2 * NBD, 512, 0, stream>>>(dstrec, dstCur, xb, out, n);
    } else if (ws_size >= need_fp) {
        // R8's proven fp32 path: cursor[n] | deg_out[n] | edge_src[n*CAP]
        int* cursor   = (int*)d_ws;
        int* deg_out  = cursor + n;
        int* edge_src = deg_out + n;

        hipMemsetAsync(cursor, 0, 2 * (size_t)n * sizeof(int), stream);
        {
            int block = 256, grid = (nE + block - 1) / block;
            bucket_kernel<<<grid, block, 0, stream>>>(src, dst, cursor, deg_out, edge_src, nE);
        }
        {
            int block = 256, grid = (n + 3) / 4;
            gather_cap_kernel<<<grid, block, 0, stream>>>(feat, edge_src, cursor, deg_out, out, n);
        }
    }
}

// Round 13
// 150.147 us; speedup vs baseline: 1.0169x; 1.0081x over previous
//
#include <hip/hip_runtime.h>
#include <hip/hip_bf16.h>

#define N_NODES 100000
#define D_FEAT 64
#define CAP 64          // fallback path only
#define NBD 784         // dst buckets of 128 nodes: 784*128 = 100352 >= n
#define DB_CAP 3072     // per-dst-bucket record cap (mean 2176, +19 sigma) == LDS CSR cap
#define RPT 6           // records per thread in binGather: RPT*512 = 3072 = DB_CAP
#define NBS 392         // src buckets of 256 nodes: 392*256 = 100352 >= n+1
#define SB_CAP 5500     // per-src-bucket record cap (mean 4336, +17 sigma)
#define PT 512          // partition threads per block
#define EPT 7           // edges register-cached per thread; chunk = EPT*PT = 3584
                        // NOTE round 9: chunk/NBD is the flush run length (4.6
                        // here); EPT=4 + NBD=1568 gave runs of 1.3 -> scatter
                        // returned, partition 30->54 us.  Keep this pairing.

typedef unsigned int uint;
typedef unsigned short ushort;

// fp32 -> bf16 round-to-nearest-even
__device__ __forceinline__ uint f2bf(float f) {
    uint u = __float_as_uint(f);
    return (u + 0x7fffu + ((u >> 16) & 1u)) >> 16;
}

// ========== pass 1: coarse partition with LDS-staged coalesced flush =======
// (round-8 proven form: rank-capture + bucket-sorted LDS staging + linear
// flush.  All per-edge atomics in LDS -- rounds 2+4 lessons.)
__global__ __launch_bounds__(PT) void
partition_kernel(const int* __restrict__ src, const int* __restrict__ dst,
                 int* __restrict__ dstCur, int* __restrict__ srcCur,
                 uint* __restrict__ dstrec, ushort* __restrict__ srcrec,
                 int nE) {
    __shared__ int hd[NBD], bd[NBD], hs[NBS], bs[NBS];   // 9.4 KB
    __shared__ uint2 pairD[EPT * PT];                    // 28 KB, reused for src
    const int t = threadIdx.x;
    const int wv = t >> 6, lane = t & 63;
    for (int i = t; i < NBD; i += PT) hd[i] = 0;
    for (int i = t; i < NBS; i += PT) hs[i] = 0;
    __syncthreads();
    const int beg = blockIdx.x * (EPT * PT);
    const int tot = min(nE - beg, EPT * PT);             // valid edges this block
    int se[EPT], de[EPT], rd[EPT], rs[EPT];
#pragma unroll
    for (int k = 0; k < EPT; ++k) {
        int e = beg + t + k * PT;
        int s = 0, d = 0, r1 = 0, r2 = 0;
        if (e < nE) {
            s = src[e]; d = dst[e];                // coalesced
            r1 = atomicAdd(&hd[d >> 7], 1);        // rank within (block, dst-bucket)
            r2 = atomicAdd(&hs[s >> 8], 1);        // rank within (block, src-bucket)
        }
        se[k] = s; de[k] = d; rd[k] = r1; rs[k] = r2;
    }
    __syncthreads();
    for (int i = t; i < NBD; i += PT) bd[i] = atomicAdd(&dstCur[i], hd[i]);
    for (int i = t; i < NBS; i += PT) bs[i] = atomicAdd(&srcCur[i], hs[i]);
    __syncthreads();
    // in-place exclusive scans: hd/hs become LDS-CSR bases (wave 0: dst, wave 1: src)
    if (wv == 0) {
        int carry = 0;
        for (int c0 = 0; c0 < NBD; c0 += 64) {
            int idx = c0 + lane;
            int v = (idx < NBD) ? hd[idx] : 0;
            int sc = v;
            for (int d = 1; d < 64; d <<= 1) {
                int u = __shfl_up(sc, d, 64);
                if (lane >= d) sc += u;
            }
            if (idx < NBD) hd[idx] = sc - v + carry;     // exclusive
            carry += __shfl(sc, 63, 64);
        }
    } else if (wv == 1) {
        int carry = 0;
        for (int c0 = 0; c0 < NBS; c0 += 64) {
            int idx = c0 + lane;
            int v = (idx < NBS) ? hs[idx] : 0;
            int sc = v;
            for (int d = 1; d < 64; d <<= 1) {
                int u = __shfl_up(sc, d, 64);
                if (lane >= d) sc += u;
            }
            if (idx < NBS) hs[idx] = sc - v + carry;
            carry += __shfl(sc, 63, 64);
        }
    }
    __syncthreads();
    // stage dst records bucket-sorted: LDS pos = scanD[b]+rank; addr = global slot
#pragma unroll
    for (int k = 0; k < EPT; ++k) {
        int e = beg + t + k * PT;
        if (e < nE) {
            int d = de[k], s = se[k];
            int b = d >> 7;
            int p = bd[b] + rd[k];
            uint addr = (p < DB_CAP) ? (uint)(b * DB_CAP + p) : 0xFFFFFFFFu;
            uint2 pr; pr.x = addr; pr.y = ((uint)(d & 127) << 17) | (uint)s;  // s < 2^17
            pairD[hd[b] + rd[k]] = pr;
        }
    }
    __syncthreads();
    for (int j = t; j < tot; j += PT) {                  // coalesced flush
        uint2 pr = pairD[j];
        if (pr.x != 0xFFFFFFFFu) dstrec[pr.x] = pr.y;
    }
    __syncthreads();                                     // before buffer reuse
    // stage src records (packed addr<<8 | payload; addr < 2.16M < 2^24)
    uint* bufS = (uint*)pairD;
#pragma unroll
    for (int k = 0; k < EPT; ++k) {
        int e = beg + t + k * PT;
        if (e < nE) {
            int s = se[k];
            int b2 = s >> 8;
            int p2 = bs[b2] + rs[k];
            uint addr = (p2 < SB_CAP) ? (uint)(b2 * SB_CAP + p2) : 0xFFFFFFu;
            bufS[hs[b2] + rs[k]] = (addr << 8) | (uint)(s & 255);
        }
    }
    __syncthreads();
    for (int j = t; j < tot; j += PT) {
        uint v = bufS[j];
        uint a = v >> 8;
        if (a < (uint)(NBS * SB_CAP)) srcrec[a] = (ushort)(v & 255);
    }
}

// ========== pass 2: src-degree histogram + prescale (half-bucket blocks) ===
// (round-10 proven: 2 blocks per 256-node bucket, grid 784 = 3.06/CU)
__global__ __launch_bounds__(512) void
prescale_kernel(const ushort* __restrict__ srcrec, const int* __restrict__ srcCur,
                const float* __restrict__ feat, uint2* __restrict__ xb, int n) {
    __shared__ int lc[128];
    const int t = threadIdx.x;
    const int b = blockIdx.x >> 1;                // bucket
    const int hb = (blockIdx.x & 1) << 7;         // half selector: 0 or 128
    const int base = (b << 8) + hb;
    if (t < 128) lc[t] = 0;
    __syncthreads();
    int cnt = min(srcCur[b], SB_CAP);
    const uint* rec2 = (const uint*)(srcrec + (size_t)b * SB_CAP);  // SB_CAP even -> aligned
    const int pairs = cnt >> 1;
    for (int i = t; i < pairs; i += 512) {
        uint rr = rec2[i];
        int a = (int)(rr & 0xFFu);
        int c = (int)((rr >> 16) & 0xFFu);
        if ((a & 128) == hb) atomicAdd(&lc[a & 127], 1);
        if ((c & 128) == hb) atomicAdd(&lc[c & 127], 1);
    }
    if ((cnt & 1) && t == 0) {
        int a = srcrec[(size_t)b * SB_CAP + cnt - 1];
        if ((a & 128) == hb) atomicAdd(&lc[a & 127], 1);
    }
    __syncthreads();
    const int rows = min(128, n + 1 - base);      // includes pad row n; <=0 past it
    const int d4 = t & 15;
    for (int r = t >> 4; r < rows; r += 32) {     // coalesced 1KB/wave
        const int row = base + r;
        uint2 o;
        if (row == n) {
            o.x = 0u; o.y = 0u;
        } else {
            float w = rsqrtf((float)max(lc[r], 1));
            float4 v = ((const float4*)feat)[(size_t)row * 16 + d4];
            o.x = f2bf(w * v.x) | (f2bf(w * v.y) << 16);
            o.y = f2bf(w * v.z) | (f2bf(w * v.w) << 16);
        }
        xb[(size_t)row * 16 + d4] = o;
    }
}

// ========== pass 3: fused bin + gather, one block per 128-node dst bucket ==
// Round-10 proven shape (full bucket, grid 784; round 12's half-split was
// neutral) + NEW: register-staged records with rank-capture (partition's
// round-6 trick applied here).  Records are read from global ONCE into
// 6 regs/thread; the histogram atomicAdd returns each record's within-node
// rank; after the scan, placement is a pure LDS store at off[node]+rank.
// Deletes the 8.7 MB global re-read and 1.7M placement atomics.
// Phase B: uint2/16-lane rows, 4 loads in flight (round-8 proven).
__global__ __launch_bounds__(512) void
binGather_kernel(const uint* __restrict__ dstrec, const int* __restrict__ dstCur,
                 const uint2* __restrict__ xb, float* __restrict__ out, int n) {
    __shared__ int cnt[128], off[128];
    __shared__ int eLDS[DB_CAP];                       // 12 KB
    const int t = threadIdx.x;
    const int b = blockIdx.x;
    const int base = b << 7;
    if (t < 128) cnt[t] = 0;
    __syncthreads();
    const int nr = min(dstCur[b], DB_CAP);
    const uint* rec = dstrec + (size_t)b * DB_CAP;
    uint re[RPT]; int rk[RPT];
#pragma unroll
    for (int k = 0; k < RPT; ++k) {                    // single coalesced read + rank
        int i = t + k * 512;
        uint r = 0; int rr = 0;
        if (i < nr) {
            r = rec[i];
            rr = atomicAdd(&cnt[r >> 17], 1);          // rank within node
        }
        re[k] = r; rk[k] = rr;
    }
    __syncthreads();
    if (t < 64) {                                      // wave-0 exclusive scan of cnt[0..127]
        int v0 = cnt[t], v1 = cnt[64 + t];
        int s0 = v0, s1 = v1;
        for (int d = 1; d < 64; d <<= 1) {
            int u0 = __shfl_up(s0, d, 64);
            int u1 = __shfl_up(s1, d, 64);
            if (t >= d) { s0 += u0; s1 += u1; }
        }
        int tot0 = __shfl(s0, 63, 64);
        off[t]      = s0 - v0;
        off[64 + t] = tot0 + s1 - v1;                  // exclusive starts (never mutated)
    }
    __syncthreads();
#pragma unroll
    for (int k = 0; k < RPT; ++k) {                    // CSR placement: pure LDS stores
        int i = t + k * 512;
        if (i < nr) eLDS[off[re[k] >> 17] + rk[k]] = (int)(re[k] & 0x1FFFF);
    }
    __syncthreads();

#define ACC8(v)                                        \
    acc.x += __uint_as_float((v).x << 16);             \
    acc.y += __uint_as_float((v).x & 0xffff0000u);     \
    acc.z += __uint_as_float((v).y << 16);             \
    acc.w += __uint_as_float((v).y & 0xffff0000u);

    // gather: 8 waves x 16 interleaved rows; 16 lanes per row (uint2)
    const int wv = t >> 6, lane = t & 63, sub = lane >> 4, d4 = lane & 15;
    for (int k = 0; k < 16; ++k) {
        const int r = wv + (k << 3);                   // wave-uniform
        const int row = base + r;
        if (row >= n) continue;
        const int c = cnt[r];
        const int start = off[r];                      // exclusive start
        float4 acc = {0.f, 0.f, 0.f, 0.f};
        int i = sub;
        for (; i + 12 < c; i += 16) {                  // 4 rows in flight per sub-group
            int s0 = eLDS[start + i];                  // 16-lane LDS broadcast
            int s1 = eLDS[start + i + 4];
            int s2 = eLDS[start + i + 8];
            int s3 = eLDS[start + i + 12];
            uint2 v0 = xb[(size_t)s0 * 16 + d4];
            uint2 v1 = xb[(size_t)s1 * 16 + d4];
            uint2 v2 = xb[(size_t)s2 * 16 + d4];
            uint2 v3 = xb[(size_t)s3 * 16 + d4];
            ACC8(v0); ACC8(v1); ACC8(v2); ACC8(v3);
        }
        for (; i < c; i += 4) {                        // tail: 1 row in flight
            int s0 = eLDS[start + i];
            uint2 v0 = xb[(size_t)s0 * 16 + d4];
            ACC8(v0);
        }
        for (int o = 16; o < 64; o <<= 1) {            // reduce across 4 sub-groups
            acc.x += __shfl_xor(acc.x, o, 64);
            acc.y += __shfl_xor(acc.y, o, 64);
            acc.z += __shfl_xor(acc.z, o, 64);
            acc.w += __shfl_xor(acc.w, o, 64);
        }
        if (sub == 0) {
            float si = rsqrtf((float)max(c, 1));       // rs_in
            float4 rr = { acc.x * si, acc.y * si, acc.z * si, acc.w * si };
            ((float4*)out)[(size_t)row * 16 + d4] = rr;
        }
    }
#undef ACC8
}

// ========== fallback: R8's proven single-pass fp32 path ====================
__global__ void bucket_kernel(const int* __restrict__ src, const int* __restrict__ dst,
                              int* __restrict__ cursor, int* __restrict__ deg_out,
                              int* __restrict__ edge_src, int nE) {
    int e = blockIdx.x * blockDim.x + threadIdx.x;
    if (e < nE) {
        int s = src[e];
        int d = dst[e];
        atomicAdd(&deg_out[s], 1);
        int pos = atomicAdd(&cursor[d], 1);
        if (pos < CAP) edge_src[(size_t)d * CAP + pos] = s;
    }
}

__global__ void gather_cap_kernel(const float* __restrict__ feat,
                                  const int* __restrict__ edge_src,
                                  const int* __restrict__ cursor,
                                  const int* __restrict__ deg_out,
                                  float* __restrict__ out, int n) {
    int wave = (blockIdx.x * blockDim.x + threadIdx.x) >> 6;
    if (wave >= n) return;
    int lane = threadIdx.x & 63;
    int cnt = min(cursor[wave], CAP);

    int   s_l = (lane < cnt) ? edge_src[(size_t)wave * CAP + lane] : 0;
    float w_l = (lane < cnt) ? rsqrtf((float)max(deg_out[s_l], 1)) : 0.0f;

    int sub = lane >> 4;
    int d4  = lane & 15;
    float4 a0 = {0.f,0.f,0.f,0.f}, a1 = {0.f,0.f,0.f,0.f};

    for (int i = 0; i < cnt; i += 8) {
        int   s0 = __shfl(s_l, i + sub, 64);
        float w0 = __shfl(w_l, i + sub, 64);
        int   s1 = __shfl(s_l, i + sub + 4, 64);
        float w1 = __shfl(w_l, i + sub + 4, 64);
        float4 v0 = ((const float4*)feat)[(size_t)s0 * 16 + d4];
        float4 v1 = ((const float4*)feat)[(size_t)s1 * 16 + d4];
        a0.x += w0 * v0.x; a0.y += w0 * v0.y; a0.z += w0 * v0.z; a0.w += w0 * v0.w;
        a1.x += w1 * v1.x; a1.y += w1 * v1.y; a1.z += w1 * v1.z; a1.w += w1 * v1.w;
    }
    float4 acc = { a0.x + a1.x, a0.y + a1.y, a0.z + a1.z, a0.w + a1.w };
    for (int off = 16; off < 64; off <<= 1) {
        acc.x += __shfl_xor(acc.x, off, 64);
        acc.y += __shfl_xor(acc.y, off, 64);
        acc.z += __shfl_xor(acc.z, off, 64);
        acc.w += __shfl_xor(acc.w, off, 64);
    }
    if (sub == 0) {
        float si = rsqrtf((float)max(cnt, 1));
        float4 r = { acc.x * si, acc.y * si, acc.z * si, acc.w * si };
        ((float4*)out)[(size_t)wave * 16 + d4] = r;
    }
}

// ===========================================================================

extern "C" void kernel_launch(void* const* d_in, const int* in_sizes, int n_in,
                              void* d_out, int out_size, void* d_ws, size_t ws_size,
                              hipStream_t stream) {
    const float* feat = (const float*)d_in[0];
    const int*   src  = (const int*)d_in[1];
    const int*   dst  = (const int*)d_in[2];
    float* out = (float*)d_out;
    const int nE = in_sizes[1];
    const int n  = N_NODES;

    // Fast-path layout (512-B aligned sections; xb rows must not straddle
    // cache lines -- round 1 proved a misaligned xb costs ~14 us):
    //   dstCur[NBD] srcCur[NBS] | dstrec | srcrec | xb
    const size_t ctr_bytes = (NBD + NBS) * sizeof(int);               // 4704
    const size_t dr_off    = (ctr_bytes + 511) & ~(size_t)511;
    const size_t dr_sz     = (size_t)NBD * DB_CAP * sizeof(uint);     // 9,633,792
    const size_t sr_off    = dr_off + dr_sz;                          // 512-mult
    const size_t sr_sz     = (size_t)NBS * SB_CAP * sizeof(ushort);   // 4,312,000
    const size_t xb_off    = (sr_off + sr_sz + 511) & ~(size_t)511;
    const size_t xb_bytes  = (size_t)(n + 1) * 16 * sizeof(uint2);    // 12,800,128
    const size_t need_new  = xb_off + xb_bytes;                       // ~26.8 MB
    const size_t need_fp   = (size_t)n * (2 + CAP) * sizeof(int);     // ~26.4 MB

    if (ws_size >= need_new) {
        char*   W        = (char*)d_ws;
        int*    dstCur   = (int*)W;
        int*    srcCur   = dstCur + NBD;
        uint*   dstrec   = (uint*)(W + dr_off);
        ushort* srcrec   = (ushort*)(W + sr_off);
        uint2*  xb       = (uint2*)(W + xb_off);

        hipMemsetAsync(dstCur, 0, ctr_bytes, stream);
        {
            const int chunk = EPT * PT;                       // 3584
            const int grid = (nE + chunk - 1) / chunk;        // 475 for 1.7M edges
            partition_kernel<<<grid, PT, 0, stream>>>(src, dst, dstCur, srcCur,
                                                      dstrec, srcrec, nE);
        }
        prescale_kernel<<<2 * NBS, 512, 0, stream>>>(srcrec, srcCur, feat, xb, n);
        binGather_kernel<<<NBD, 512, 0, stream>>>(dstrec, dstCur, xb, out, n);
    } else if (ws_size >= need_fp) {
        // R8's proven fp32 path: cursor[n] | deg_out[n] | edge_src[n*CAP]
        int* cursor   = (int*)d_ws;
        int* deg_out  = cursor + n;
        int* edge_src = deg_out + n;

        hipMemsetAsync(cursor, 0, 2 * (size_t)n * sizeof(int), stream);
        {
            int block = 256, grid = (nE + block - 1) / block;
            bucket_kernel<<<grid, block, 0, stream>>>(src, dst, cursor, deg_out, edge_src, nE);
        }
        {
            int block = 256, grid = (n + 3) / 4;
            gather_cap_kernel<<<grid, block, 0, stream>>>(feat, edge_src, cursor, deg_out, out, n);
        }
    }
}

// Round 14
// 146.576 us; speedup vs baseline: 1.0417x; 1.0244x over previous
//
#include <hip/hip_runtime.h>
#include <hip/hip_bf16.h>

#define N_NODES 100000
#define D_FEAT 64
#define CAP 64          // fallback path only
#define NBD 784         // dst buckets of 128 nodes: 784*128 = 100352 >= n
#define DB_CAP 3072     // per-dst-bucket record cap (mean 2176, +19 sigma) == LDS CSR cap
#define RPT 6           // records per thread in binGather: RPT*512 = 3072 = DB_CAP
#define NBS 392         // src buckets of 256 nodes: 392*256 = 100352 >= n+1
#define SB_CAP 5500     // per-src-bucket record cap (mean 4336, +17 sigma)
#define PT 512          // partition threads per block
#define EPT 7           // edges register-cached per thread; chunk = EPT*PT = 3584
                        // NOTE round 9: chunk/NBD is the flush run length (4.6
                        // here); EPT=4 + NBD=1568 gave runs of 1.3 -> scatter
                        // returned, partition 30->54 us.  Keep this pairing.

typedef unsigned int uint;
typedef unsigned short ushort;

// fp32 -> bf16 round-to-nearest-even
__device__ __forceinline__ uint f2bf(float f) {
    uint u = __float_as_uint(f);
    return (u + 0x7fffu + ((u >> 16) & 1u)) >> 16;
}

// ========== pass 1: split coarse partition (concurrent dst / src blocks) ===
// Round-14: the dst-record and src-record pipelines share no data and no
// LDS state; the fused kernel chained them through ~9 barrier phases at
// 1.85 heavy blocks/CU (VALUBusy 5.8% -- dependency-bound, not pipe-bound).
// Split into two block populations in ONE dispatch: grid 950 = 3.7/CU of
// half-weight blocks, each ~5 barrier phases.  Same rank-capture + LDS
// staging + coalesced flush per side (round-8 proven).  dstrec placement is
// bit-identical to round 13.  All per-edge atomics in LDS (rounds 2+4).
__global__ __launch_bounds__(PT) void
partition_kernel(const int* __restrict__ src, const int* __restrict__ dst,
                 int* __restrict__ dstCur, int* __restrict__ srcCur,
                 uint* __restrict__ dstrec, ushort* __restrict__ srcrec,
                 int nE, int nBlkD) {
    __shared__ int hist[2 * NBD];                        // 6.3 KB (dst: hd+bd; src: hs+bs)
    __shared__ uint2 pairD[EPT * PT];                    // 28 KB (src side aliases as uint)
    const int t = threadIdx.x;
    const int lane = t & 63;

    if ((int)blockIdx.x < nBlkD) {
        // ---------------- dst-record side ----------------
        int* hd = hist;
        int* bd = hist + NBD;
        for (int i = t; i < NBD; i += PT) hd[i] = 0;
        __syncthreads();
        const int beg = blockIdx.x * (EPT * PT);
        const int tot = min(nE - beg, EPT * PT);
        int se[EPT], de[EPT], rd[EPT];
#pragma unroll
        for (int k = 0; k < EPT; ++k) {
            int e = beg + t + k * PT;
            int s = 0, d = 0, r1 = 0;
            if (e < nE) {
                s = src[e]; d = dst[e];                // coalesced
                r1 = atomicAdd(&hd[d >> 7], 1);        // rank within (block, dst-bucket)
            }
            se[k] = s; de[k] = d; rd[k] = r1;
        }
        __syncthreads();
        for (int i = t; i < NBD; i += PT) bd[i] = atomicAdd(&dstCur[i], hd[i]);
        __syncthreads();
        if (t < 64) {                                  // wave-0 exclusive scan -> LDS CSR bases
            int carry = 0;
            for (int c0 = 0; c0 < NBD; c0 += 64) {
                int idx = c0 + lane;
                int v = (idx < NBD) ? hd[idx] : 0;
                int sc = v;
                for (int d = 1; d < 64; d <<= 1) {
                    int u = __shfl_up(sc, d, 64);
                    if (lane >= d) sc += u;
                }
                if (idx < NBD) hd[idx] = sc - v + carry;
                carry += __shfl(sc, 63, 64);
            }
        }
        __syncthreads();
#pragma unroll
        for (int k = 0; k < EPT; ++k) {                // stage bucket-sorted
            int e = beg + t + k * PT;
            if (e < nE) {
                int d = de[k], s = se[k];
                int b = d >> 7;
                int p = bd[b] + rd[k];
                uint addr = (p < DB_CAP) ? (uint)(b * DB_CAP + p) : 0xFFFFFFFFu;
                uint2 pr; pr.x = addr; pr.y = ((uint)(d & 127) << 17) | (uint)s;  // s < 2^17
                pairD[hd[b] + rd[k]] = pr;
            }
        }
        __syncthreads();
        for (int j = t; j < tot; j += PT) {            // coalesced flush
            uint2 pr = pairD[j];
            if (pr.x != 0xFFFFFFFFu) dstrec[pr.x] = pr.y;
        }
    } else {
        // ---------------- src-record side ----------------
        int* hs = hist;
        int* bs = hist + NBS;
        uint* bufS = (uint*)pairD;                     // 14 KB used
        for (int i = t; i < NBS; i += PT) hs[i] = 0;
        __syncthreads();
        const int beg = (blockIdx.x - nBlkD) * (EPT * PT);
        const int tot = min(nE - beg, EPT * PT);
        int se[EPT], rs[EPT];
#pragma unroll
        for (int k = 0; k < EPT; ++k) {
            int e = beg + t + k * PT;
            int s = 0, r2 = 0;
            if (e < nE) {
                s = src[e];                            // coalesced (only src needed)
                r2 = atomicAdd(&hs[s >> 8], 1);        // rank within (block, src-bucket)
            }
            se[k] = s; rs[k] = r2;
        }
        __syncthreads();
        for (int i = t; i < NBS; i += PT) bs[i] = atomicAdd(&srcCur[i], hs[i]);
        __syncthreads();
        if (t < 64) {                                  // wave-0 exclusive scan
            int carry = 0;
            for (int c0 = 0; c0 < NBS; c0 += 64) {
                int idx = c0 + lane;
                int v = (idx < NBS) ? hs[idx] : 0;
                int sc = v;
                for (int d = 1; d < 64; d <<= 1) {
                    int u = __shfl_up(sc, d, 64);
                    if (lane >= d) sc += u;
                }
                if (idx < NBS) hs[idx] = sc - v + carry;
                carry += __shfl(sc, 63, 64);
            }
        }
        __syncthreads();
#pragma unroll
        for (int k = 0; k < EPT; ++k) {                // stage (packed addr<<8 | payload)
            int e = beg + t + k * PT;
            if (e < nE) {
                int s = se[k];
                int b2 = s >> 8;
                int p2 = bs[b2] + rs[k];
                uint addr = (p2 < SB_CAP) ? (uint)(b2 * SB_CAP + p2) : 0xFFFFFFu;
                bufS[hs[b2] + rs[k]] = (addr << 8) | (uint)(s & 255);
            }
        }
        __syncthreads();
        for (int j = t; j < tot; j += PT) {            // coalesced flush
            uint v = bufS[j];
            uint a = v >> 8;
            if (a < (uint)(NBS * SB_CAP)) srcrec[a] = (ushort)(v & 255);
        }
    }
}

// ========== pass 2: src-degree histogram + prescale (half-bucket blocks) ===
// (round-10 proven: 2 blocks per 256-node bucket, grid 784 = 3.06/CU)
__global__ __launch_bounds__(512) void
prescale_kernel(const ushort* __restrict__ srcrec, const int* __restrict__ srcCur,
                const float* __restrict__ feat, uint2* __restrict__ xb, int n) {
    __shared__ int lc[128];
    const int t = threadIdx.x;
    const int b = blockIdx.x >> 1;                // bucket
    const int hb = (blockIdx.x & 1) << 7;         // half selector: 0 or 128
    const int base = (b << 8) + hb;
    if (t < 128) lc[t] = 0;
    __syncthreads();
    int cnt = min(srcCur[b], SB_CAP);
    const uint* rec2 = (const uint*)(srcrec + (size_t)b * SB_CAP);  // SB_CAP even -> aligned
    const int pairs = cnt >> 1;
    for (int i = t; i < pairs; i += 512) {
        uint rr = rec2[i];
        int a = (int)(rr & 0xFFu);
        int c = (int)((rr >> 16) & 0xFFu);
        if ((a & 128) == hb) atomicAdd(&lc[a & 127], 1);
        if ((c & 128) == hb) atomicAdd(&lc[c & 127], 1);
    }
    if ((cnt & 1) && t == 0) {
        int a = srcrec[(size_t)b * SB_CAP + cnt - 1];
        if ((a & 128) == hb) atomicAdd(&lc[a & 127], 1);
    }
    __syncthreads();
    const int rows = min(128, n + 1 - base);      // includes pad row n; <=0 past it
    const int d4 = t & 15;
    for (int r = t >> 4; r < rows; r += 32) {     // coalesced 1KB/wave
        const int row = base + r;
        uint2 o;
        if (row == n) {
            o.x = 0u; o.y = 0u;
        } else {
            float w = rsqrtf((float)max(lc[r], 1));
            float4 v = ((const float4*)feat)[(size_t)row * 16 + d4];
            o.x = f2bf(w * v.x) | (f2bf(w * v.y) << 16);
            o.y = f2bf(w * v.z) | (f2bf(w * v.w) << 16);
        }
        xb[(size_t)row * 16 + d4] = o;
    }
}

// ========== pass 3: fused bin + gather, one block per 128-node dst bucket ==
// (round-13 form: register-staged records + rank-capture; phase B
//  uint2/16-lane rows, 4 loads in flight)
__global__ __launch_bounds__(512) void
binGather_kernel(const uint* __restrict__ dstrec, const int* __restrict__ dstCur,
                 const uint2* __restrict__ xb, float* __restrict__ out, int n) {
    __shared__ int cnt[128], off[128];
    __shared__ int eLDS[DB_CAP];                       // 12 KB
    const int t = threadIdx.x;
    const int b = blockIdx.x;
    const int base = b << 7;
    if (t < 128) cnt[t] = 0;
    __syncthreads();
    const int nr = min(dstCur[b], DB_CAP);
    const uint* rec = dstrec + (size_t)b * DB_CAP;
    uint re[RPT]; int rk[RPT];
#pragma unroll
    for (int k = 0; k < RPT; ++k) {                    // single coalesced read + rank
        int i = t + k * 512;
        uint r = 0; int rr = 0;
        if (i < nr) {
            r = rec[i];
            rr = atomicAdd(&cnt[r >> 17], 1);          // rank within node
        }
        re[k] = r; rk[k] = rr;
    }
    __syncthreads();
    if (t < 64) {                                      // wave-0 exclusive scan of cnt[0..127]
        int v0 = cnt[t], v1 = cnt[64 + t];
        int s0 = v0, s1 = v1;
        for (int d = 1; d < 64; d <<= 1) {
            int u0 = __shfl_up(s0, d, 64);
            int u1 = __shfl_up(s1, d, 64);
            if (t >= d) { s0 += u0; s1 += u1; }
        }
        int tot0 = __shfl(s0, 63, 64);
        off[t]      = s0 - v0;
        off[64 + t] = tot0 + s1 - v1;                  // exclusive starts (never mutated)
    }
    __syncthreads();
#pragma unroll
    for (int k = 0; k < RPT; ++k) {                    // CSR placement: pure LDS stores
        int i = t + k * 512;
        if (i < nr) eLDS[off[re[k] >> 17] + rk[k]] = (int)(re[k] & 0x1FFFF);
    }
    __syncthreads();

#define ACC8(v)                                        \
    acc.x += __uint_as_float((v).x << 16);             \
    acc.y += __uint_as_float((v).x & 0xffff0000u);     \
    acc.z += __uint_as_float((v).y << 16);             \
    acc.w += __uint_as_float((v).y & 0xffff0000u);

    // gather: 8 waves x 16 interleaved rows; 16 lanes per row (uint2)
    const int wv = t >> 6, lane = t & 63, sub = lane >> 4, d4 = lane & 15;
    for (int k = 0; k < 16; ++k) {
        const int r = wv + (k << 3);                   // wave-uniform
        const int row = base + r;
        if (row >= n) continue;
        const int c = cnt[r];
        const int start = off[r];                      // exclusive start
        float4 acc = {0.f, 0.f, 0.f, 0.f};
        int i = sub;
        for (; i + 12 < c; i += 16) {                  // 4 rows in flight per sub-group
            int s0 = eLDS[start + i];                  // 16-lane LDS broadcast
            int s1 = eLDS[start + i + 4];
            int s2 = eLDS[start + i + 8];
            int s3 = eLDS[start + i + 12];
            uint2 v0 = xb[(size_t)s0 * 16 + d4];
            uint2 v1 = xb[(size_t)s1 * 16 + d4];
            uint2 v2 = xb[(size_t)s2 * 16 + d4];
            uint2 v3 = xb[(size_t)s3 * 16 + d4];
            ACC8(v0); ACC8(v1); ACC8(v2); ACC8(v3);
        }
        for (; i < c; i += 4) {                        // tail: 1 row in flight
            int s0 = eLDS[start + i];
            uint2 v0 = xb[(size_t)s0 * 16 + d4];
            ACC8(v0);
        }
        for (int o = 16; o < 64; o <<= 1) {            // reduce across 4 sub-groups
            acc.x += __shfl_xor(acc.x, o, 64);
            acc.y += __shfl_xor(acc.y, o, 64);
            acc.z += __shfl_xor(acc.z, o, 64);
            acc.w += __shfl_xor(acc.w, o, 64);
        }
        if (sub == 0) {
            float si = rsqrtf((float)max(c, 1));       // rs_in
            float4 rr = { acc.x * si, acc.y * si, acc.z * si, acc.w * si };
            ((float4*)out)[(size_t)row * 16 + d4] = rr;
        }
    }
#undef ACC8
}

// ========== fallback: R8's proven single-pass fp32 path ====================
__global__ void bucket_kernel(const int* __restrict__ src, const int* __restrict__ dst,
                              int* __restrict__ cursor, int* __restrict__ deg_out,
                              int* __restrict__ edge_src, int nE) {
    int e = blockIdx.x * blockDim.x + threadIdx.x;
    if (e < nE) {
        int s = src[e];
        int d = dst[e];
        atomicAdd(&deg_out[s], 1);
        int pos = atomicAdd(&cursor[d], 1);
        if (pos < CAP) edge_src[(size_t)d * CAP + pos] = s;
    }
}

__global__ void gather_cap_kernel(const float* __restrict__ feat,
                                  const int* __restrict__ edge_src,
                                  const int* __restrict__ cursor,
                                  const int* __restrict__ deg_out,
                                  float* __restrict__ out, int n) {
    int wave = (blockIdx.x * blockDim.x + threadIdx.x) >> 6;
    if (wave >= n) return;
    int lane = threadIdx.x & 63;
    int cnt = min(cursor[wave], CAP);

    int   s_l = (lane < cnt) ? edge_src[(size_t)wave * CAP + lane] : 0;
    float w_l = (lane < cnt) ? rsqrtf((float)max(deg_out[s_l], 1)) : 0.0f;

    int sub = lane >> 4;
    int d4  = lane & 15;
    float4 a0 = {0.f,0.f,0.f,0.f}, a1 = {0.f,0.f,0.f,0.f};

    for (int i = 0; i < cnt; i += 8) {
        int   s0 = __shfl(s_l, i + sub, 64);
        float w0 = __shfl(w_l, i + sub, 64);
        int   s1 = __shfl(s_l, i + sub + 4, 64);
        float w1 = __shfl(w_l, i + sub + 4, 64);
        float4 v0 = ((const float4*)feat)[(size_t)s0 * 16 + d4];
        float4 v1 = ((const float4*)feat)[(size_t)s1 * 16 + d4];
        a0.x += w0 * v0.x; a0.y += w0 * v0.y; a0.z += w0 * v0.z; a0.w += w0 * v0.w;
        a1.x += w1 * v1.x; a1.y += w1 * v1.y; a1.z += w1 * v1.z; a1.w += w1 * v1.w;
    }
    float4 acc = { a0.x + a1.x, a0.y + a1.y, a0.z + a1.z, a0.w + a1.w };
    for (int off = 16; off < 64; off <<= 1) {
        acc.x += __shfl_xor(acc.x, off, 64);
        acc.y += __shfl_xor(acc.y, off, 64);
        acc.z += __shfl_xor(acc.z, off, 64);
        acc.w += __shfl_xor(acc.w, off, 64);
    }
    if (sub == 0) {
        float si = rsqrtf((float)max(cnt, 1));
        float4 r = { acc.x * si, acc.y * si, acc.z * si, acc.w * si };
        ((float4*)out)[(size_t)wave * 16 + d4] = r;
    }
}

// ===========================================================================

extern "C" void kernel_launch(void* const* d_in, const int* in_sizes, int n_in,
                              void* d_out, int out_size, void* d_ws, size_t ws_size,
                              hipStream_t stream) {
    const float* feat = (const float*)d_in[0];
    const int*   src  = (const int*)d_in[1];
    const int*   dst  = (const int*)d_in[2];
    float* out = (float*)d_out;
    const int nE = in_sizes[1];
    const int n  = N_NODES;

    // Fast-path layout (512-B aligned sections; xb rows must not straddle
    // cache lines -- round 1 proved a misaligned xb costs ~14 us):
    //   dstCur[NBD] srcCur[NBS] | dstrec | srcrec | xb
    const size_t ctr_bytes = (NBD + NBS) * sizeof(int);               // 4704
    const size_t dr_off    = (ctr_bytes + 511) & ~(size_t)511;
    const size_t dr_sz     = (size_t)NBD * DB_CAP * sizeof(uint);     // 9,633,792
    const size_t sr_off    = dr_off + dr_sz;                          // 512-mult
    const size_t sr_sz     = (size_t)NBS * SB_CAP * sizeof(ushort);   // 4,312,000
    const size_t xb_off    = (sr_off + sr_sz + 511) & ~(size_t)511;
    const size_t xb_bytes  = (size_t)(n + 1) * 16 * sizeof(uint2);    // 12,800,128
    const size_t need_new  = xb_off + xb_bytes;                       // ~26.8 MB
    const size_t need_fp   = (size_t)n * (2 + CAP) * sizeof(int);     // ~26.4 MB

    if (ws_size >= need_new) {
        char*   W        = (char*)d_ws;
        int*    dstCur   = (int*)W;
        int*    srcCur   = dstCur + NBD;
        uint*   dstrec   = (uint*)(W + dr_off);
        ushort* srcrec   = (ushort*)(W + sr_off);
        uint2*  xb       = (uint2*)(W + xb_off);

        hipMemsetAsync(dstCur, 0, ctr_bytes, stream);
        {
            const int chunk = EPT * PT;                       // 3584
            const int nBlkD = (nE + chunk - 1) / chunk;       // 475 for 1.7M edges
            partition_kernel<<<2 * nBlkD, PT, 0, stream>>>(src, dst, dstCur, srcCur,
                                                           dstrec, srcrec, nE, nBlkD);
        }
        prescale_kernel<<<2 * NBS, 512, 0, stream>>>(srcrec, srcCur, feat, xb, n);
        binGather_kernel<<<NBD, 512, 0, stream>>>(dstrec, dstCur, xb, out, n);
    } else if (ws_size >= need_fp) {
        // R8's proven fp32 path: cursor[n] | deg_out[n] | edge_src[n*CAP]
        int* cursor   = (int*)d_ws;
        int* deg_out  = cursor + n;
        int* edge_src = deg_out + n;

        hipMemsetAsync(cursor, 0, 2 * (size_t)n * sizeof(int), stream);
        {
            int block = 256, grid = (nE + block - 1) / block;
            bucket_kernel<<<grid, block, 0, stream>>>(src, dst, cursor, deg_out, edge_src, nE);
        }
        {
            int block = 256, grid = (n + 3) / 4;
            gather_cap_kernel<<<grid, block, 0, stream>>>(feat, edge_src, cursor, deg_out, out, n);
        }
    }
}